// Round 7
// baseline (134.413 us; speedup 1.0000x reference)
//
#include <hip/hip_runtime.h>

static constexpr int NN = 100000;   // nodes
static constexpr int NE = 500000;   // edges
static constexpr int D  = 32;       // channels
static constexpr int NR = 16;       // relations
static constexpr int HB = 256;      // histogram / scatter blocks
static constexpr int ES = (NE + HB - 1) / HB;   // edges per hist/scatter block
static constexpr int NY = 80;       // blocks per type in k_edge -> 1280 blocks

// ---------------- K1: h = x @ W  (+ hist + d_out zeroing) ---------------
__global__ __launch_bounds__(256) void k_xw_hist(const float* __restrict__ x,
                                                 const float* __restrict__ W,
                                                 const int* __restrict__ et,
                                                 float* __restrict__ h,
                                                 int* __restrict__ cnt,
                                                 float* __restrict__ outz) {
    __shared__ float sW[D * D];
    __shared__ int lh[NR];
    if (threadIdx.x < NR) lh[threadIdx.x] = 0;
    for (int i = threadIdx.x; i < D * D; i += 256) sW[i] = W[i];
    __syncthreads();

    {   // zero d_out (grid-stride) — replaces the 12.8 MB memset dispatch
        float4* oz = reinterpret_cast<float4*>(outz);
        const int total4 = NN * D / 4;
        for (int i = blockIdx.x * 256 + threadIdx.x; i < total4; i += gridDim.x * 256)
            oz[i] = make_float4(0.f, 0.f, 0.f, 0.f);
    }

    if (blockIdx.x < HB) {   // 256 blocks histogram -> 4096 global atomics
        const int beg = blockIdx.x * ES, end = min(beg + ES, NE);
        for (int e = beg + (int)threadIdx.x; e < end; e += 256)
            atomicAdd(&lh[et[e]], 1);
    }

    const int n = blockIdx.x * 256 + threadIdx.x;
    if (n < NN) {
        float xr[D];
        const float4* xv = reinterpret_cast<const float4*>(x + (size_t)n * D);
        #pragma unroll
        for (int k = 0; k < 8; ++k) {
            float4 v = xv[k];
            xr[4*k+0] = v.x; xr[4*k+1] = v.y; xr[4*k+2] = v.z; xr[4*k+3] = v.w;
        }
        float4* hv = reinterpret_cast<float4*>(h + (size_t)n * D);
        #pragma unroll
        for (int oc = 0; oc < 8; ++oc) {
            float a0 = 0.f, a1 = 0.f, a2 = 0.f, a3 = 0.f;
            #pragma unroll
            for (int i = 0; i < D; ++i) {
                float xi = xr[i];
                a0 += xi * sW[i*D + 4*oc + 0];
                a1 += xi * sW[i*D + 4*oc + 1];
                a2 += xi * sW[i*D + 4*oc + 2];
                a3 += xi * sW[i*D + 4*oc + 3];
            }
            hv[oc] = make_float4(a0, a1, a2, a3);
        }
    }
    __syncthreads();
    if (blockIdx.x < HB && threadIdx.x < NR && lh[threadIdx.x] > 0)
        atomicAdd(&cnt[threadIdx.x], lh[threadIdx.x]);
}

// ---------------- K2a: scatter into type buckets (range-grab) -----------
__global__ __launch_bounds__(256) void k_scatter(const int* __restrict__ ei,
                                                 const int* __restrict__ et,
                                                 const int* __restrict__ cnt,
                                                 int* __restrict__ cursor,
                                                 int2* __restrict__ rec) {
    __shared__ int lh[NR], lcur[NR], soff[NR];
    if (threadIdx.x < NR) lh[threadIdx.x] = 0;
    if (threadIdx.x == 0) {
        int s = 0;
        for (int t = 0; t < NR; ++t) { soff[t] = s; s += cnt[t]; }
    }
    __syncthreads();
    const int beg = blockIdx.x * ES, end = min(beg + ES, NE);
    for (int e = beg + (int)threadIdx.x; e < end; e += 256)
        atomicAdd(&lh[et[e]], 1);
    __syncthreads();
    if (threadIdx.x < NR)
        lcur[threadIdx.x] = (lh[threadIdx.x] > 0)
                          ? soff[threadIdx.x] + atomicAdd(&cursor[threadIdx.x], lh[threadIdx.x])
                          : 0;
    __syncthreads();
    for (int e = beg + (int)threadIdx.x; e < end; e += 256) {
        const int t = et[e];
        const int pos = atomicAdd(&lcur[t], 1);
        rec[pos] = make_int2(ei[e], ei[NE + e]);
    }
}

// ---------------- K2b: per-edge matvec + scatter-add (pipelined) --------
__global__ __launch_bounds__(256) void k_edge(const float* __restrict__ h,
                                              const int2* __restrict__ rec,
                                              const int* __restrict__ cnt,
                                              const float* __restrict__ rel,
                                              float* __restrict__ acc) {
    const int t = blockIdx.x & (NR - 1);
    const int c = blockIdx.x >> 4;          // 0..NY-1
    __shared__ float sh[8][8][D];           // 8 KB: [half][slot][chan]
    const int o = threadIdx.x & 31;
    const int g = threadIdx.x >> 5;
    float Rc[32];
    const float* Rt = rel + t * 1024;
    #pragma unroll
    for (int i = 0; i < 32; ++i) Rc[i] = Rt[i * 32 + o];

    int beg = 0;
    #pragma unroll
    for (int u = 0; u < NR; ++u) beg += (u < t) ? cnt[u] : 0;
    const int end = beg + cnt[t];

    const int cntt = end - beg;
    const int L  = (cntt + NY - 1) / NY;
    const int b0 = beg + c * L;
    const int b1 = min(b0 + L, end);
    if (b0 >= b1) return;
    const int S  = ((b1 - b0) + 7) / 8;
    const int m0 = b0 + g * S;
    const int m1 = min(m0 + S, b1);
    if (m0 >= m1) return;                   // no barriers below: safe

    int2 r0[8], r1[8];
    float hv[8];
    #pragma unroll
    for (int j = 0; j < 8; ++j) r0[j] = rec[min(m0 + j, m1 - 1)];
    #pragma unroll
    for (int j = 0; j < 8; ++j) hv[j] = h[(size_t)r0[j].x * D + o];
    #pragma unroll
    for (int j = 0; j < 8; ++j) r1[j] = rec[min(m0 + 8 + j, m1 - 1)];

    for (int e = m0; e < m1; e += 8) {
        #pragma unroll
        for (int j = 0; j < 8; ++j) sh[g][j][o] = hv[j];
        int d8[8];
        #pragma unroll
        for (int j = 0; j < 8; ++j) d8[j] = r0[j].y;
        if (e + 8 < m1) {                   // 2-level prefetch
            #pragma unroll
            for (int j = 0; j < 8; ++j) hv[j] = h[(size_t)r1[j].x * D + o];
            #pragma unroll
            for (int j = 0; j < 8; ++j) r0[j] = r1[j];
            #pragma unroll
            for (int j = 0; j < 8; ++j) r1[j] = rec[min(e + 16 + j, m1 - 1)];
        }
        __asm__ volatile("s_waitcnt lgkmcnt(0)" ::: "memory");
        float a[8] = {0.f, 0.f, 0.f, 0.f, 0.f, 0.f, 0.f, 0.f};
        #pragma unroll
        for (int j = 0; j < 8; ++j) {
            const float4* row = reinterpret_cast<const float4*>(sh[g][j]);
            #pragma unroll
            for (int q = 0; q < 8; ++q) {
                const float4 v = row[q];
                a[j] = fmaf(v.x, Rc[4*q+0], a[j]);
                a[j] = fmaf(v.y, Rc[4*q+1], a[j]);
                a[j] = fmaf(v.z, Rc[4*q+2], a[j]);
                a[j] = fmaf(v.w, Rc[4*q+3], a[j]);
            }
        }
        #pragma unroll
        for (int j = 0; j < 8; ++j)
            if (e + j < m1)
                atomicAdd(acc + (size_t)d8[j] * D + o, a[j]);
    }
}

// ---------------- K3a: scores + per-block online (max, sum-exp) ---------
__global__ __launch_bounds__(256) void k_score(const float* __restrict__ acc,
                                               const float* __restrict__ att,
                                               float* __restrict__ scores,
                                               float* __restrict__ pmax,
                                               float* __restrict__ psum) {
    __shared__ float sA[D];
    __shared__ float shm[4], shs[4];
    if (threadIdx.x < D) sA[threadIdx.x] = att[threadIdx.x];
    __syncthreads();
    const int n = blockIdx.x * 256 + threadIdx.x;
    float s = -3.4e38f;
    if (n < NN) {
        const float4* av = reinterpret_cast<const float4*>(acc + (size_t)n * D);
        float v0 = 0.f;
        #pragma unroll
        for (int k = 0; k < 8; ++k) {
            float4 v = av[k];
            v0 += v.x * sA[4*k+0] + v.y * sA[4*k+1] + v.z * sA[4*k+2] + v.w * sA[4*k+3];
        }
        scores[n] = v0;
        s = v0;
    }
    float m = s;
    #pragma unroll
    for (int offt = 32; offt > 0; offt >>= 1)
        m = fmaxf(m, __shfl_down(m, offt, 64));
    if ((threadIdx.x & 63) == 0) shm[threadIdx.x >> 6] = m;
    __syncthreads();
    const float bm = fmaxf(fmaxf(shm[0], shm[1]), fmaxf(shm[2], shm[3]));
    float e = (n < NN) ? expf(s - bm) : 0.f;
    #pragma unroll
    for (int offt = 32; offt > 0; offt >>= 1)
        e += __shfl_down(e, offt, 64);
    if ((threadIdx.x & 63) == 0) shs[threadIdx.x >> 6] = e;
    __syncthreads();
    if (threadIdx.x == 0) {
        pmax[blockIdx.x] = bm;
        psum[blockIdx.x] = shs[0] + shs[1] + shs[2] + shs[3];
    }
}

// ---------------- K3b: fused combine + scale ----------------------------
__global__ __launch_bounds__(256) void k_final(float* __restrict__ out,
                                               const float* __restrict__ scores,
                                               const float* __restrict__ pmax,
                                               const float* __restrict__ psum,
                                               int nb) {
    __shared__ float shm[4], shs[4];
    const int tid = threadIdx.x;
    float m = -3.4e38f, s = 0.f;
    for (int i = tid; i < nb; i += 256) {
        const float mi = pmax[i], si = psum[i];
        const float M = fmaxf(m, mi);
        s = s * expf(m - M) + si * expf(mi - M);
        m = M;
    }
    #pragma unroll
    for (int offt = 32; offt > 0; offt >>= 1) {
        const float mo = __shfl_down(m, offt, 64);
        const float so = __shfl_down(s, offt, 64);
        const float M = fmaxf(m, mo);
        s = s * expf(m - M) + so * expf(mo - M);
        m = M;
    }
    if ((tid & 63) == 0) { shm[tid >> 6] = m; shs[tid >> 6] = s; }
    __syncthreads();
    float M = shm[0], S = shs[0];
    #pragma unroll
    for (int w = 1; w < 4; ++w) {
        const float Mn = fmaxf(M, shm[w]);
        S = S * expf(M - Mn) + shs[w] * expf(shm[w] - Mn);
        M = Mn;
    }
    const int idx = blockIdx.x * 256 + tid;        // float4 index, exact grid
    const int n = idx >> 3;
    const float w = expf(scores[n] - M) / S;
    float4* p = reinterpret_cast<float4*>(out);
    float4 v = p[idx];
    v.x = fmaxf(v.x * w, 0.f);
    v.y = fmaxf(v.y * w, 0.f);
    v.z = fmaxf(v.z * w, 0.f);
    v.w = fmaxf(v.w * w, 0.f);
    p[idx] = v;
}

extern "C" void kernel_launch(void* const* d_in, const int* in_sizes, int n_in,
                              void* d_out, int out_size, void* d_ws, size_t ws_size,
                              hipStream_t stream) {
    const float* x   = (const float*)d_in[0];
    const int*   ei  = (const int*)  d_in[1];
    const int*   et  = (const int*)  d_in[2];
    const float* W   = (const float*)d_in[3];
    const float* rel = (const float*)d_in[4];
    const float* att = (const float*)d_in[5];
    float* out = (float*)d_out;

    // ws layout: h[NN*D] | rec[NE int2] | cnt[16] | cursor[16]
    //            | pmax[512] | psum[512];  scores overlays rec after k_edge
    float* h      = (float*)d_ws;
    int2*  rec    = (int2*)(h + (size_t)NN * D);
    int*   cnt    = (int*)(rec + NE);
    int*   cursor = cnt + NR;
    float* pmax   = (float*)(cursor + NR);
    float* psum   = pmax + 512;
    float* scores = (float*)rec;

    hipMemsetAsync(cnt, 0, 2 * NR * sizeof(int), stream);   // cnt + cursor

    const int nb_n = (NN + 255) / 256;           // 391
    k_xw_hist<<<nb_n, 256, 0, stream>>>(x, W, et, h, cnt, out);
    k_scatter<<<HB, 256, 0, stream>>>(ei, et, cnt, cursor, rec);
    k_edge<<<NR * NY, 256, 0, stream>>>(h, rec, cnt, rel, out);
    k_score<<<nb_n, 256, 0, stream>>>(out, att, scores, pmax, psum);
    k_final<<<(NN * (D / 4)) / 256, 256, 0, stream>>>(out, scores, pmax, psum, nb_n);
}